// Round 5
// baseline (659.200 us; speedup 1.0000x reference)
//
#include <hip/hip_runtime.h>

typedef short v8s __attribute__((ext_vector_type(8)));
typedef float v4f __attribute__((ext_vector_type(4)));

#define T_TOK 2048
#define DD 2048
#define FF 4096
#define EE 8
#define BM 128
#define BN 128
#define BK 64
#define MT_MAX 40
#define MAXROWS 5120

// workspace layout (bytes)
#define WS_COUNTS 0
#define WS_FILL   32
#define WS_ROWOFF 64
#define WS_TOPE   128
#define WS_TOPW   (WS_TOPE + T_TOK * 2 * 4)   // 16512
#define WS_IDS    (WS_TOPW + T_TOK * 2 * 4)   // 32896
#define WS_WTS    (WS_IDS + MAXROWS * 4)      // 53376
#define WS_ZERO   (WS_WTS + MAXROWS * 4)      // 73856 bytes zeroed each launch
#define WS_H      73984ul                     // 256-aligned; bf16 H[5120][4096]

// B-tile swizzle (bf16 [row][64k], 128B rows) — verified round 4.
#define SWZ(r, kb) ((r) * 128 + ((kb) ^ ((((r) ^ ((r) >> 3)) & 7) << 4)))

static __device__ __forceinline__ short f2bf(float f) {
  return __builtin_bit_cast(short, static_cast<__bf16>(f));
}

// async global->LDS, 16B per lane; LDS dest must be wave-uniform base
// (HW adds lane*16). Per-lane GLOBAL address is free -> source pre-swizzle.
static __device__ __forceinline__ void gload_lds16(const void* g, void* l) {
  __builtin_amdgcn_global_load_lds(
      (const __attribute__((address_space(1))) unsigned int*)g,
      (__attribute__((address_space(3))) unsigned int*)l, 16, 0, 0);
}

// ---------------- router: fp32 logits, softmax, top-2 ----------------
__global__ __launch_bounds__(256) void router_k(
    const float* __restrict__ x, const float* __restrict__ gw,
    int* __restrict__ counts, int* __restrict__ tope, float* __restrict__ topw) {
  const int lane = threadIdx.x & 63;
  const int t = blockIdx.x * 4 + (threadIdx.x >> 6);
  if (t >= T_TOK) return;
  float acc[EE] = {0.f, 0.f, 0.f, 0.f, 0.f, 0.f, 0.f, 0.f};
  const float* xr = x + (size_t)t * DD;
  for (int i = 0; i < DD / 64; ++i) {
    int k = i * 64 + lane;
    float xv = xr[k];
    const v4f* g = (const v4f*)(gw + (size_t)k * EE);
    v4f g0 = g[0], g1 = g[1];
    acc[0] += xv * g0[0]; acc[1] += xv * g0[1]; acc[2] += xv * g0[2]; acc[3] += xv * g0[3];
    acc[4] += xv * g1[0]; acc[5] += xv * g1[1]; acc[6] += xv * g1[2]; acc[7] += xv * g1[3];
  }
  #pragma unroll
  for (int e = 0; e < EE; ++e) {
    #pragma unroll
    for (int off = 32; off > 0; off >>= 1) acc[e] += __shfl_xor(acc[e], off);
  }
  if (lane == 0) {
    float m = acc[0];
    #pragma unroll
    for (int e = 1; e < EE; ++e) m = fmaxf(m, acc[e]);
    float p[EE], s = 0.f;
    #pragma unroll
    for (int e = 0; e < EE; ++e) { p[e] = expf(acc[e] - m); s += p[e]; }
    float inv = 1.f / s;
    #pragma unroll
    for (int e = 0; e < EE; ++e) p[e] *= inv;
    int e1 = 0;
    #pragma unroll
    for (int e = 1; e < EE; ++e) if (p[e] > p[e1]) e1 = e;
    int e2 = (e1 == 0) ? 1 : 0;
    #pragma unroll
    for (int e = 0; e < EE; ++e) if (e != e1 && p[e] > p[e2]) e2 = e;
    tope[2 * t] = e1;  tope[2 * t + 1] = e2;
    topw[2 * t] = p[e1]; topw[2 * t + 1] = p[e2];
    atomicAdd(&counts[e1], 1);
    atomicAdd(&counts[e2], 1);
  }
}

// ---------------- per-expert padded row offsets ----------------
__global__ void offsets_k(const int* __restrict__ counts, int* __restrict__ rowoff) {
  if (threadIdx.x == 0) {
    int off = 0;
    #pragma unroll
    for (int e = 0; e < EE; ++e) {
      rowoff[e] = off;
      off += ((counts[e] + BM - 1) / BM) * BM;
    }
  }
}

// ---------------- scatter token ids/weights into expert-sorted slots ----------------
__global__ __launch_bounds__(256) void scatter_k(
    const int* __restrict__ tope, const float* __restrict__ topw,
    const int* __restrict__ rowoff, int* __restrict__ fill,
    int* __restrict__ ids, float* __restrict__ wts) {
  const int t = blockIdx.x * 256 + threadIdx.x;
  if (t >= T_TOK) return;
  #pragma unroll
  for (int j = 0; j < 2; ++j) {
    int e = tope[2 * t + j];
    int pos = rowoff[e] + atomicAdd(&fill[e], 1);
    ids[pos] = t;
    wts[pos] = topw[2 * t + j];
  }
}

static __device__ __forceinline__ int find_expert(
    const int* counts, const int* rowoff, int mt) {
  int expert = -1;
  #pragma unroll
  for (int e = 0; e < EE; ++e) {
    int rs = rowoff[e];
    int tl = (counts[e] + BM - 1) / BM;
    if (mt * BM >= rs && mt * BM < rs + tl * BM) expert = e;
  }
  return expert;
}

// XCD-aware bijective chunk swizzle; mt-fastest so each XCD owns a band of
// nt columns (B-panel L2 reuse). Requires nwg % 8 == 0 (1280 / 640: yes).
static __device__ __forceinline__ void xcd_map(int* nt, int* mt) {
  int gx = gridDim.x, gy = gridDim.y;
  int nwg = gx * gy;
  int lin = blockIdx.y * gx + blockIdx.x;
  int q = nwg >> 3;
  int s = (lin & 7) * q + (lin >> 3);
  *nt = s / gy;
  *mt = s % gy;
}

// ---------------- GEMM1: H = silu(X@W1) * (X@W3), bf16 out ----------------
// A: fp32 via global_load_lds (source-swizzled chunks), cvt at use.
// B: one 16-v4f batch (w1+w3) -> cvt -> swizzled bf16 LDS.
__global__ __launch_bounds__(256, 2) void gemm1_k(
    const float* __restrict__ x, const float* __restrict__ w1,
    const float* __restrict__ w3, const int* __restrict__ counts,
    const int* __restrict__ rowoff, const int* __restrict__ ids,
    unsigned short* __restrict__ H) {
  int nt, mt;
  xcd_map(&nt, &mt);
  const int expert = find_expert(counts, rowoff, mt);
  if (expert < 0) return;
  const int m0 = mt * BM, n0 = nt * BN;

  __shared__ float sA[BM * BK];              // 32 KB fp32, chunk-swizzled
  __shared__ unsigned short sB0[BN * BK];    // 16 KB
  __shared__ unsigned short sB1[BN * BK];    // 16 KB  (total 64 KB)

  const int tid = threadIdx.x;
  const int lane = tid & 63;
  const int wid = tid >> 6;
  const int wm = (wid >> 1) * 64, wn = (wid & 1) * 64;
  const int lr = lane & 15, lg = lane >> 4;

  // ---- A via global_load_lds: wave wid covers rows wid*32..+31 (8 instrs x 4 rows).
  // lane: lrow = lane>>4 (0..3), chunk c = lane&15 (16B = 4 floats).
  // source pre-swizzle: fetch global chunk (c ^ (row&7)) so the LINEAR LDS
  // position c holds global chunk c^sigma -> read applies same XOR.
  const int awr0 = wid * 32;
  const int alrow = lane >> 4;
  const int achk = lane & 15;
  const float* abp[8];
  #pragma unroll
  for (int i = 0; i < 8; ++i) {
    int lrow_full = i * 4 + alrow;                 // LDS row within wave block (mod 8 == row&7)
    int sg = lrow_full & 7;
    abp[i] = x + (size_t)ids[m0 + awr0 + lrow_full] * DD + ((achk ^ sg) << 2);
  }

  // ---- B staging: thread covers 4 f-rows x 8 k per mat; all 16 v4f one batch.
  const int b_f4 = (tid & 31) * 4;
  const int b_k8 = (tid >> 5) * 8;
  const float* wb1 = w1 + (size_t)expert * DD * FF + n0 + b_f4 + (size_t)b_k8 * FF;
  const float* wb3 = w3 + (size_t)expert * DD * FF + n0 + b_f4 + (size_t)b_k8 * FF;

  v4f acc1[4][4], acc3[4][4];
  #pragma unroll
  for (int i = 0; i < 4; ++i)
    #pragma unroll
    for (int j = 0; j < 4; ++j) {
      acc1[i][j] = (v4f){0.f, 0.f, 0.f, 0.f};
      acc3[i][j] = (v4f){0.f, 0.f, 0.f, 0.f};
    }

  for (int kt = 0; kt < DD / BK; ++kt) {
    // A: 8 async 1KB wave-loads, zero VGPR round-trip
    #pragma unroll
    for (int i = 0; i < 8; ++i)
      gload_lds16(abp[i] + (size_t)kt * BK, (char*)sA + (awr0 + i * 4) * 256);
    // B: single 16-load window, then cvt+write
    {
      const float* p1 = wb1 + (size_t)kt * BK * FF;
      const float* p3 = wb3 + (size_t)kt * BK * FF;
      v4f r1[8], r3[8];
      #pragma unroll
      for (int j = 0; j < 8; ++j) r1[j] = *(const v4f*)(p1 + (size_t)j * FF);
      #pragma unroll
      for (int j = 0; j < 8; ++j) r3[j] = *(const v4f*)(p3 + (size_t)j * FF);
      #pragma unroll
      for (int c = 0; c < 4; ++c) {
        v8s h1, h3;
        #pragma unroll
        for (int j = 0; j < 8; ++j) { h1[j] = f2bf(r1[j][c]); h3[j] = f2bf(r3[j][c]); }
        *(v8s*)((char*)sB0 + SWZ(b_f4 + c, b_k8 * 2)) = h1;
        *(v8s*)((char*)sB1 + SWZ(b_f4 + c, b_k8 * 2)) = h3;
      }
    }
    __syncthreads();   // drains vmcnt (incl. global_load_lds) + lgkmcnt
    #pragma unroll
    for (int ks = 0; ks < 2; ++ks) {
      const int kb = ks * 64 + lg * 16;       // byte col for B (bf16)
      v8s b1[4], b3[4];
      #pragma unroll
      for (int n = 0; n < 4; ++n) {
        b1[n] = *(const v8s*)((const char*)sB0 + SWZ(wn + n * 16 + lr, kb));
        b3[n] = *(const v8s*)((const char*)sB1 + SWZ(wn + n * 16 + lr, kb));
      }
      #pragma unroll
      for (int m = 0; m < 4; ++m) {
        const int row = wm + m * 16 + lr;
        const int sg = row & 7;
        const int g0 = ks * 8 + lg * 2;       // 16B chunk index of k-lo half
        v4f c0 = *(const v4f*)((const char*)sA + row * 256 + ((g0 ^ sg) << 4));
        v4f c1 = *(const v4f*)((const char*)sA + row * 256 + (((g0 + 1) ^ sg) << 4));
        v8s av;
        av[0] = f2bf(c0[0]); av[1] = f2bf(c0[1]); av[2] = f2bf(c0[2]); av[3] = f2bf(c0[3]);
        av[4] = f2bf(c1[0]); av[5] = f2bf(c1[1]); av[6] = f2bf(c1[2]); av[7] = f2bf(c1[3]);
        #pragma unroll
        for (int n = 0; n < 4; ++n) {
          acc1[m][n] = __builtin_amdgcn_mfma_f32_16x16x32_bf16(av, b1[n], acc1[m][n], 0, 0, 0);
          acc3[m][n] = __builtin_amdgcn_mfma_f32_16x16x32_bf16(av, b3[n], acc3[m][n], 0, 0, 0);
        }
      }
    }
    __syncthreads();
  }
  #pragma unroll
  for (int m = 0; m < 4; ++m)
    #pragma unroll
    for (int n = 0; n < 4; ++n)
      #pragma unroll
      for (int r = 0; r < 4; ++r) {
        int row = wm + m * 16 + lg * 4 + r;
        int col = wn + n * 16 + lr;
        float g = acc1[m][n][r];
        float u = acc3[m][n][r];
        float hv = (g / (1.f + expf(-g))) * u;
        H[(size_t)(m0 + row) * FF + (n0 + col)] = (unsigned short)f2bf(hv);
      }
}

// ---------------- GEMM2: out[tok] += w * (H @ W2) ----------------
// A = H (bf16) via global_load_lds (source-swizzled); B = w2, 8-v4f batch.
__global__ __launch_bounds__(256, 2) void gemm2_k(
    const unsigned short* __restrict__ H, const float* __restrict__ w2,
    const int* __restrict__ counts, const int* __restrict__ rowoff,
    const int* __restrict__ ids, const float* __restrict__ wts,
    float* __restrict__ out) {
  int nt, mt;
  xcd_map(&nt, &mt);
  const int expert = find_expert(counts, rowoff, mt);
  if (expert < 0) return;
  const int m0 = mt * BM, n0 = nt * BN;

  __shared__ unsigned short sA[BM * BK];     // 16 KB bf16, chunk-swizzled
  __shared__ unsigned short sB[BN * BK];     // 16 KB

  const int tid = threadIdx.x;
  const int lane = tid & 63;
  const int wid = tid >> 6;
  const int wm = (wid >> 1) * 64, wn = (wid & 1) * 64;
  const int lr = lane & 15, lg = lane >> 4;

  // A: wave wid covers rows wid*32..+31 (4 instrs x 8 rows); row = 128B = 8 chunks.
  const int awr0 = wid * 32;
  const int alrow = lane >> 3;               // 0..7
  const int achk = lane & 7;                 // 16B chunk (8 bf16)
  const unsigned short* abp[4];
  #pragma unroll
  for (int i = 0; i < 4; ++i) {
    int lrow_full = i * 8 + alrow;
    int sg = lrow_full & 7;                  // == alrow
    abp[i] = H + (size_t)(m0 + awr0 + lrow_full) * FF + ((achk ^ sg) << 3);
  }

  const int b_f4 = (tid & 31) * 4;   // output cols (d)
  const int b_k8 = (tid >> 5) * 8;   // k rows (f)
  const float* wb = w2 + (size_t)expert * FF * DD + n0 + b_f4 + (size_t)b_k8 * DD;

  v4f acc[4][4];
  #pragma unroll
  for (int i = 0; i < 4; ++i)
    #pragma unroll
    for (int j = 0; j < 4; ++j) acc[i][j] = (v4f){0.f, 0.f, 0.f, 0.f};

  for (int kt = 0; kt < FF / BK; ++kt) {
    #pragma unroll
    for (int i = 0; i < 4; ++i)
      gload_lds16(abp[i] + (size_t)kt * BK, (char*)sA + (awr0 + i * 8) * 128);
    {
      const float* p = wb + (size_t)kt * BK * DD;
      v4f r[8];
      #pragma unroll
      for (int j = 0; j < 8; ++j) r[j] = *(const v4f*)(p + (size_t)j * DD);
      #pragma unroll
      for (int c = 0; c < 4; ++c) {
        v8s h;
        #pragma unroll
        for (int j = 0; j < 8; ++j) h[j] = f2bf(r[j][c]);
        *(v8s*)((char*)sB + SWZ(b_f4 + c, b_k8 * 2)) = h;
      }
    }
    __syncthreads();
    #pragma unroll
    for (int ks = 0; ks < 2; ++ks) {
      const int kb = ks * 64 + lg * 16;
      v8s a[4], b[4];
      #pragma unroll
      for (int m = 0; m < 4; ++m) {
        const int row = wm + m * 16 + lr;
        const int g = ks * 4 + lg;           // 16B chunk idx within 8-chunk row
        a[m] = *(const v8s*)((const char*)sA + row * 128 + ((g ^ (row & 7)) << 4));
      }
      #pragma unroll
      for (int n = 0; n < 4; ++n)
        b[n] = *(const v8s*)((const char*)sB + SWZ(wn + n * 16 + lr, kb));
      #pragma unroll
      for (int m = 0; m < 4; ++m)
        #pragma unroll
        for (int n = 0; n < 4; ++n)
          acc[m][n] = __builtin_amdgcn_mfma_f32_16x16x32_bf16(a[m], b[n], acc[m][n], 0, 0, 0);
    }
    __syncthreads();
  }
  #pragma unroll
  for (int m = 0; m < 4; ++m)
    #pragma unroll
    for (int r = 0; r < 4; ++r) {
      int row = m0 + wm + m * 16 + lg * 4 + r;
      float wgt = wts[row];
      if (wgt != 0.f) {   // skip zero-weight padding rows (exact 0 from memset)
        float* orow = out + (size_t)ids[row] * DD + n0 + wn + lr;
        #pragma unroll
        for (int n = 0; n < 4; ++n)
          atomicAdd(orow + n * 16, wgt * acc[m][n][r]);
      }
    }
}

extern "C" void kernel_launch(void* const* d_in, const int* in_sizes, int n_in,
                              void* d_out, int out_size, void* d_ws, size_t ws_size,
                              hipStream_t stream) {
  const float* x  = (const float*)d_in[0];
  const float* gw = (const float*)d_in[1];
  const float* w1 = (const float*)d_in[2];
  const float* w3 = (const float*)d_in[3];
  const float* w2 = (const float*)d_in[4];
  float* out = (float*)d_out;
  char* ws = (char*)d_ws;

  int*   counts = (int*)(ws + WS_COUNTS);
  int*   fill   = (int*)(ws + WS_FILL);
  int*   rowoff = (int*)(ws + WS_ROWOFF);
  int*   tope   = (int*)(ws + WS_TOPE);
  float* topw   = (float*)(ws + WS_TOPW);
  int*   ids    = (int*)(ws + WS_IDS);
  float* wts    = (float*)(ws + WS_WTS);
  unsigned short* H = (unsigned short*)(ws + WS_H);

  hipMemsetAsync(ws, 0, WS_ZERO, stream);
  hipMemsetAsync(d_out, 0, (size_t)out_size * sizeof(float), stream);

  router_k<<<T_TOK / 4, 256, 0, stream>>>(x, gw, counts, tope, topw);
  offsets_k<<<1, 64, 0, stream>>>(counts, rowoff);
  scatter_k<<<T_TOK / 256, 256, 0, stream>>>(tope, topw, rowoff, fill, ids, wts);
  gemm1_k<<<dim3(FF / BN, MT_MAX), 256, 0, stream>>>(x, w1, w3, counts, rowoff, ids, H);
  gemm2_k<<<dim3(DD / BN, MT_MAX), 256, 0, stream>>>(H, w2, counts, rowoff, ids, wts, out);
}

// Round 6
// 649.347 us; speedup vs baseline: 1.0152x; 1.0152x over previous
//
#include <hip/hip_runtime.h>

typedef short v8s __attribute__((ext_vector_type(8)));
typedef short v4s __attribute__((ext_vector_type(4)));
typedef float v4f __attribute__((ext_vector_type(4)));

#define T_TOK 2048
#define DD 2048
#define FF 4096
#define EE 8
#define BM 128
#define MT_MAX 40
#define MAXROWS 5120

// workspace layout (bytes)
#define WS_COUNTS 0
#define WS_FILL   32
#define WS_ROWOFF 64
#define WS_TOPE   128
#define WS_TOPW   (WS_TOPE + T_TOK * 2 * 4)   // 16512
#define WS_IDS    (WS_TOPW + T_TOK * 2 * 4)   // 32896
#define WS_WTS    (WS_IDS + MAXROWS * 4)      // 53376
#define WS_ZERO   (WS_WTS + MAXROWS * 4)      // 73856 bytes zeroed each launch
#define WS_XB     73984ul                     // bf16 X [2048][2048] = 8 MB
#define WS_GH     (WS_XB + 8388608ul)         // bf16 G/H in-place [5120][4096] = 42 MB

// B-tile LDS address: [f][32k bf16] rows of 64B, 4×16B chunks, 2-bit XOR swizzle.
#define BSW(f) (((f) ^ ((f) >> 3)) & 3)
#define BS(f, kb) ((f) * 64 + ((((kb) >> 4) ^ BSW(f)) << 4) + ((kb) & 15))

static __device__ __forceinline__ short f2bf(float f) {
  return __builtin_bit_cast(short, static_cast<__bf16>(f));
}
static __device__ __forceinline__ float bf2f(unsigned short u) {
  return __builtin_bit_cast(float, ((unsigned)u) << 16);
}

// async global->LDS 16B/lane; dest = wave-uniform base + lane*16 (HW).
static __device__ __forceinline__ void gload_lds16(const void* g, void* l) {
  __builtin_amdgcn_global_load_lds(
      (const __attribute__((address_space(1))) unsigned int*)g,
      (__attribute__((address_space(3))) unsigned int*)l, 16, 0, 0);
}

// ---------------- X -> bf16 ----------------
__global__ __launch_bounds__(256) void xbf_k(const float* __restrict__ x,
                                             unsigned short* __restrict__ xb) {
  const int i = (blockIdx.x * 256 + threadIdx.x) * 8;
  v4f a = *(const v4f*)(x + i);
  v4f b = *(const v4f*)(x + i + 4);
  v8s h;
  h[0] = f2bf(a[0]); h[1] = f2bf(a[1]); h[2] = f2bf(a[2]); h[3] = f2bf(a[3]);
  h[4] = f2bf(b[0]); h[5] = f2bf(b[1]); h[6] = f2bf(b[2]); h[7] = f2bf(b[3]);
  *(v8s*)(xb + i) = h;
}

// ---------------- router: fp32 logits, softmax, top-2 ----------------
__global__ __launch_bounds__(256) void router_k(
    const float* __restrict__ x, const float* __restrict__ gw,
    int* __restrict__ counts, int* __restrict__ tope, float* __restrict__ topw) {
  const int lane = threadIdx.x & 63;
  const int t = blockIdx.x * 4 + (threadIdx.x >> 6);
  if (t >= T_TOK) return;
  float acc[EE] = {0.f, 0.f, 0.f, 0.f, 0.f, 0.f, 0.f, 0.f};
  const float* xr = x + (size_t)t * DD;
  for (int i = 0; i < DD / 64; ++i) {
    int k = i * 64 + lane;
    float xv = xr[k];
    const v4f* g = (const v4f*)(gw + (size_t)k * EE);
    v4f g0 = g[0], g1 = g[1];
    acc[0] += xv * g0[0]; acc[1] += xv * g0[1]; acc[2] += xv * g0[2]; acc[3] += xv * g0[3];
    acc[4] += xv * g1[0]; acc[5] += xv * g1[1]; acc[6] += xv * g1[2]; acc[7] += xv * g1[3];
  }
  #pragma unroll
  for (int e = 0; e < EE; ++e) {
    #pragma unroll
    for (int off = 32; off > 0; off >>= 1) acc[e] += __shfl_xor(acc[e], off);
  }
  if (lane == 0) {
    float m = acc[0];
    #pragma unroll
    for (int e = 1; e < EE; ++e) m = fmaxf(m, acc[e]);
    float p[EE], s = 0.f;
    #pragma unroll
    for (int e = 0; e < EE; ++e) { p[e] = expf(acc[e] - m); s += p[e]; }
    float inv = 1.f / s;
    #pragma unroll
    for (int e = 0; e < EE; ++e) p[e] *= inv;
    int e1 = 0;
    #pragma unroll
    for (int e = 1; e < EE; ++e) if (p[e] > p[e1]) e1 = e;
    int e2 = (e1 == 0) ? 1 : 0;
    #pragma unroll
    for (int e = 0; e < EE; ++e) if (e != e1 && p[e] > p[e2]) e2 = e;
    tope[2 * t] = e1;  tope[2 * t + 1] = e2;
    topw[2 * t] = p[e1]; topw[2 * t + 1] = p[e2];
    atomicAdd(&counts[e1], 1);
    atomicAdd(&counts[e2], 1);
  }
}

// ---------------- per-expert padded row offsets ----------------
__global__ void offsets_k(const int* __restrict__ counts, int* __restrict__ rowoff) {
  if (threadIdx.x == 0) {
    int off = 0;
    #pragma unroll
    for (int e = 0; e < EE; ++e) {
      rowoff[e] = off;
      off += ((counts[e] + BM - 1) / BM) * BM;
    }
  }
}

// ---------------- scatter token ids/weights into expert-sorted slots ----------------
__global__ __launch_bounds__(256) void scatter_k(
    const int* __restrict__ tope, const float* __restrict__ topw,
    const int* __restrict__ rowoff, int* __restrict__ fill,
    int* __restrict__ ids, float* __restrict__ wts) {
  const int t = blockIdx.x * 256 + threadIdx.x;
  if (t >= T_TOK) return;
  #pragma unroll
  for (int j = 0; j < 2; ++j) {
    int e = tope[2 * t + j];
    int pos = rowoff[e] + atomicAdd(&fill[e], 1);
    ids[pos] = t;
    wts[pos] = topw[2 * t + j];
  }
}

static __device__ __forceinline__ int find_expert(
    const int* counts, const int* rowoff, int mt) {
  int expert = -1;
  #pragma unroll
  for (int e = 0; e < EE; ++e) {
    int rs = rowoff[e];
    int tl = (counts[e] + BM - 1) / BM;
    if (mt * BM >= rs && mt * BM < rs + tl * BM) expert = e;
  }
  return expert;
}

// XCD-aware bijective swizzle (nwg % 8 == 0 for both grids).
static __device__ __forceinline__ void xcd_map(int* nt, int* mt) {
  int gx = gridDim.x, gy = gridDim.y;
  int nwg = gx * gy;
  int lin = blockIdx.y * gx + blockIdx.x;
  int q = nwg >> 3;
  int s = (lin & 7) * q + (lin >> 3);
  *nt = s / gy;
  *mt = s % gy;
}

// ============ GEMM1 (two passes): phase0: GH = silu(Xb@W1)
//              phase1: GH *= (Xb@W3)  (in-place, same addresses) ============
// 128x128 tile, BK=32, 4 waves, T3 2-phase dbuf.
// A: bf16 via global_load_lds (source-chunk pre-swizzled, gathered token rows).
// B: 4 v4f fp32 -> cvt -> swizzled bf16 LDS.
__global__ __launch_bounds__(256, 4) void g1_k(
    const unsigned short* __restrict__ xb, const float* __restrict__ w,
    const int* __restrict__ counts, const int* __restrict__ rowoff,
    const int* __restrict__ ids, unsigned short* __restrict__ gh, int domul) {
  int nt, mt;
  xcd_map(&nt, &mt);
  const int expert = find_expert(counts, rowoff, mt);
  if (expert < 0) return;
  const int m0 = mt * BM, n0 = nt * 128;

  __shared__ char smem[32768];   // 2 bufs x (A 8KB | B 8KB)

  const int tid = threadIdx.x;
  const int lane = tid & 63;
  const int wid = tid >> 6;
  const int lr = lane & 15, lg = lane >> 4;
  const int wm = (wid >> 1) * 64, wn = (wid & 1) * 64;

  // A gload: wave covers rows wid*32..+31, 2 instr x (16 rows x 4 chunks of 16B)
  const unsigned short* asrc[2];
  #pragma unroll
  for (int i = 0; i < 2; ++i) {
    int row = wid * 32 + i * 16 + (lane >> 2);
    int ch = (lane & 3) ^ (row & 3);          // source pre-swizzle
    asrc[i] = xb + (size_t)ids[m0 + row] * DD + ch * 8;
  }

  // B: thread covers f4..f4+3 (cols) x k4..k4+3
  const int f4 = (tid & 31) * 4, k4 = (tid >> 5) * 4;
  const float* bsrc = w + (size_t)expert * DD * FF + (size_t)k4 * FF + n0 + f4;

  v4f rb[4];
  #define G1_AL(KT, BUF) { _Pragma("unroll") for (int i = 0; i < 2; ++i)        \
      gload_lds16(asrc[i] + (size_t)(KT) * 32,                                  \
                  smem + (BUF) * 16384 + (wid * 32 + i * 16) * 64); }
  #define G1_BL(KT) { const float* p_ = bsrc + (size_t)(KT) * 32 * FF;          \
      _Pragma("unroll") for (int j = 0; j < 4; ++j)                             \
        rb[j] = *(const v4f*)(p_ + (size_t)j * FF); }
  #define G1_BW(BUF) { char* bb_ = smem + (BUF) * 16384 + 8192;                 \
      _Pragma("unroll") for (int c = 0; c < 4; ++c) { v4s h_;                   \
        _Pragma("unroll") for (int j = 0; j < 4; ++j) h_[j] = f2bf(rb[j][c]);   \
        *(v4s*)(bb_ + BS(f4 + c, k4 * 2)) = h_; } }

  v4f acc[4][4];
  #pragma unroll
  for (int i = 0; i < 4; ++i)
    #pragma unroll
    for (int j = 0; j < 4; ++j) acc[i][j] = (v4f){0.f, 0.f, 0.f, 0.f};

  G1_AL(0, 0); G1_BL(0); G1_BW(0);
  __syncthreads();

  const int NKT = DD / 32;  // 64
  #pragma unroll 2
  for (int kt = 0; kt < NKT; ++kt) {
    const int cur = kt & 1;
    if (kt + 1 < NKT) { G1_AL(kt + 1, cur ^ 1); G1_BL(kt + 1); }
    const char* ab = smem + cur * 16384;
    const char* bb = ab + 8192;
    v8s bfr[4];
    #pragma unroll
    for (int n = 0; n < 4; ++n) {
      int f = wn + n * 16 + lr;
      bfr[n] = *(const v8s*)(bb + f * 64 + ((lg ^ BSW(f)) << 4));
    }
    #pragma unroll
    for (int m = 0; m < 4; ++m) {
      int row = wm + m * 16 + lr;
      v8s av = *(const v8s*)(ab + row * 64 + ((lg ^ (row & 3)) << 4));
      #pragma unroll
      for (int n = 0; n < 4; ++n)
        acc[m][n] = __builtin_amdgcn_mfma_f32_16x16x32_bf16(av, bfr[n], acc[m][n], 0, 0, 0);
    }
    __syncthreads();               // reads of cur done; kt+1 loads landed (overlapped)
    if (kt + 1 < NKT) G1_BW(cur ^ 1);
    __syncthreads();
  }

  #pragma unroll
  for (int m = 0; m < 4; ++m)
    #pragma unroll
    for (int n = 0; n < 4; ++n)
      #pragma unroll
      for (int r = 0; r < 4; ++r) {
        int row = wm + m * 16 + lg * 4 + r;
        int col = wn + n * 16 + lr;
        size_t idx = (size_t)(m0 + row) * FF + (n0 + col);
        float v = acc[m][n][r];
        if (!domul) {
          gh[idx] = (unsigned short)f2bf(v / (1.f + expf(-v)));   // silu
        } else {
          gh[idx] = (unsigned short)f2bf(bf2f(gh[idx]) * v);      // G * up
        }
      }
}

// ============ GEMM2: out[tok] += wgt * (GH @ W2) ============
// Same shape: 128x128, BK=32, dbuf. A = GH bf16 (contiguous rows) gload_lds.
__global__ __launch_bounds__(256, 4) void g2_k(
    const unsigned short* __restrict__ gh, const float* __restrict__ w2,
    const int* __restrict__ counts, const int* __restrict__ rowoff,
    const int* __restrict__ ids, const float* __restrict__ wts,
    float* __restrict__ out) {
  int nt, mt;
  xcd_map(&nt, &mt);
  const int expert = find_expert(counts, rowoff, mt);
  if (expert < 0) return;
  const int m0 = mt * BM, n0 = nt * 128;

  __shared__ char smem[32768];

  const int tid = threadIdx.x;
  const int lane = tid & 63;
  const int wid = tid >> 6;
  const int lr = lane & 15, lg = lane >> 4;
  const int wm = (wid >> 1) * 64, wn = (wid & 1) * 64;

  const unsigned short* asrc[2];
  #pragma unroll
  for (int i = 0; i < 2; ++i) {
    int row = wid * 32 + i * 16 + (lane >> 2);
    int ch = (lane & 3) ^ (row & 3);
    asrc[i] = gh + (size_t)(m0 + row) * FF + ch * 8;
  }

  const int d4 = (tid & 31) * 4, k4 = (tid >> 5) * 4;
  const float* bsrc = w2 + (size_t)expert * FF * DD + (size_t)k4 * DD + n0 + d4;

  v4f rb[4];
  #define G2_AL(KT, BUF) { _Pragma("unroll") for (int i = 0; i < 2; ++i)        \
      gload_lds16(asrc[i] + (size_t)(KT) * 32,                                  \
                  smem + (BUF) * 16384 + (wid * 32 + i * 16) * 64); }
  #define G2_BL(KT) { const float* p_ = bsrc + (size_t)(KT) * 32 * DD;          \
      _Pragma("unroll") for (int j = 0; j < 4; ++j)                             \
        rb[j] = *(const v4f*)(p_ + (size_t)j * DD); }
  #define G2_BW(BUF) { char* bb_ = smem + (BUF) * 16384 + 8192;                 \
      _Pragma("unroll") for (int c = 0; c < 4; ++c) { v4s h_;                   \
        _Pragma("unroll") for (int j = 0; j < 4; ++j) h_[j] = f2bf(rb[j][c]);   \
        *(v4s*)(bb_ + BS(d4 + c, k4 * 2)) = h_; } }

  v4f acc[4][4];
  #pragma unroll
  for (int i = 0; i < 4; ++i)
    #pragma unroll
    for (int j = 0; j < 4; ++j) acc[i][j] = (v4f){0.f, 0.f, 0.f, 0.f};

  G2_AL(0, 0); G2_BL(0); G2_BW(0);
  __syncthreads();

  const int NKT = FF / 32;  // 128
  #pragma unroll 2
  for (int kt = 0; kt < NKT; ++kt) {
    const int cur = kt & 1;
    if (kt + 1 < NKT) { G2_AL(kt + 1, cur ^ 1); G2_BL(kt + 1); }
    const char* ab = smem + cur * 16384;
    const char* bb = ab + 8192;
    v8s bfr[4];
    #pragma unroll
    for (int n = 0; n < 4; ++n) {
      int f = wn + n * 16 + lr;
      bfr[n] = *(const v8s*)(bb + f * 64 + ((lg ^ BSW(f)) << 4));
    }
    #pragma unroll
    for (int m = 0; m < 4; ++m) {
      int row = wm + m * 16 + lr;
      v8s av = *(const v8s*)(ab + row * 64 + ((lg ^ (row & 3)) << 4));
      #pragma unroll
      for (int n = 0; n < 4; ++n)
        acc[m][n] = __builtin_amdgcn_mfma_f32_16x16x32_bf16(av, bfr[n], acc[m][n], 0, 0, 0);
    }
    __syncthreads();
    if (kt + 1 < NKT) G2_BW(cur ^ 1);
    __syncthreads();
  }

  #pragma unroll
  for (int m = 0; m < 4; ++m)
    #pragma unroll
    for (int r = 0; r < 4; ++r) {
      int row = m0 + wm + m * 16 + lg * 4 + r;
      float wgt = wts[row];
      if (wgt != 0.f) {   // skip zero-weight padding rows
        float* orow = out + (size_t)ids[row] * DD + n0 + wn + lr;
        #pragma unroll
        for (int n = 0; n < 4; ++n)
          atomicAdd(orow + n * 16, wgt * acc[m][n][r]);
      }
    }
}

extern "C" void kernel_launch(void* const* d_in, const int* in_sizes, int n_in,
                              void* d_out, int out_size, void* d_ws, size_t ws_size,
                              hipStream_t stream) {
  const float* x  = (const float*)d_in[0];
  const float* gw = (const float*)d_in[1];
  const float* w1 = (const float*)d_in[2];
  const float* w3 = (const float*)d_in[3];
  const float* w2 = (const float*)d_in[4];
  float* out = (float*)d_out;
  char* ws = (char*)d_ws;

  int*   counts = (int*)(ws + WS_COUNTS);
  int*   fill   = (int*)(ws + WS_FILL);
  int*   rowoff = (int*)(ws + WS_ROWOFF);
  int*   tope   = (int*)(ws + WS_TOPE);
  float* topw   = (float*)(ws + WS_TOPW);
  int*   ids    = (int*)(ws + WS_IDS);
  float* wts    = (float*)(ws + WS_WTS);
  unsigned short* xb = (unsigned short*)(ws + WS_XB);
  unsigned short* gh = (unsigned short*)(ws + WS_GH);

  hipMemsetAsync(ws, 0, WS_ZERO, stream);
  hipMemsetAsync(d_out, 0, (size_t)out_size * sizeof(float), stream);

  xbf_k<<<T_TOK * DD / (256 * 8), 256, 0, stream>>>(x, xb);
  router_k<<<T_TOK / 4, 256, 0, stream>>>(x, gw, counts, tope, topw);
  offsets_k<<<1, 64, 0, stream>>>(counts, rowoff);
  scatter_k<<<T_TOK / 256, 256, 0, stream>>>(tope, topw, rowoff, fill, ids, wts);
  g1_k<<<dim3(FF / 128, MT_MAX), 256, 0, stream>>>(xb, w1, counts, rowoff, ids, gh, 0);
  g1_k<<<dim3(FF / 128, MT_MAX), 256, 0, stream>>>(xb, w3, counts, rowoff, ids, gh, 1);
  g2_k<<<dim3(DD / 128, MT_MAX), 256, 0, stream>>>(gh, w2, counts, rowoff, ids, wts, out);
}